// Round 7
// baseline (141.060 us; speedup 1.0000x reference)
//
#include <hip/hip_runtime.h>
#include <hip/hip_bf16.h>
#include <math.h>

#define T_DIM 2048
#define B_DIM 16
#define M_DIM 512
#define H_DIM 256
#define KC 512
#define K_DIM 512
#define CHUNK 64
#define NCHUNK 32
#define BK 32
#define NTILE 16            // K / BK

typedef unsigned short ushort_t;
typedef __attribute__((ext_vector_type(8))) short short8;
typedef __attribute__((ext_vector_type(8))) unsigned short ushort8;
typedef __attribute__((ext_vector_type(4))) float f32x4;

// ---- workspace layout (float offsets); total 17301504 floats = 69.2 MB ----
#define WS_CARRY 0            // 262144 floats (32*16*512)
#define WS_WB_BF 262144       // 262144 ushorts natural [j][k]
#define WS_WC_BF 393216       // 262144 ushorts natural [m][k]
#define WS_XB    524288       // 16777216 ushorts: X bf16 natural [n][k]
#define WS_BU    8912896      // 16777216 ushorts: Bu natural [n][col], then H in place

__device__ inline ushort_t f2bf(float f) {
    __hip_bfloat16 h = __float2bfloat16(f);
    return *reinterpret_cast<ushort_t*>(&h);
}
__device__ inline float bf2f(ushort_t u) {
    union { unsigned int i; float f; } v;
    v.i = ((unsigned int)u) << 16;
    return v.f;
}

// natural bf16 weights: wb[j*512+k] (j<256: gamma*B_re; else gamma*B_im),
// wc[m*512+k] = [C_re | -C_im]
__global__ void prep_w(const float* __restrict__ B_re, const float* __restrict__ B_im,
                       const float* __restrict__ gamma_log,
                       const float* __restrict__ C_re, const float* __restrict__ C_im,
                       ushort_t* __restrict__ wb, ushort_t* __restrict__ wc) {
    int idx = blockIdx.x * blockDim.x + threadIdx.x;  // 0..262143
    int j = idx >> 9;
    int k = idx & 511;
    float v;
    if (j < 256) v = expf(gamma_log[j])       * B_re[j * 512 + k];
    else         v = expf(gamma_log[j - 256]) * B_im[(j - 256) * 512 + k];
    wb[idx] = f2bf(v);
    float w;
    if (k < 256) w =  C_re[j * 256 + k];
    else         w = -C_im[j * 256 + (k - 256)];
    wc[idx] = f2bf(w);
}

// X fp32 -> bf16 natural, coalesced both sides (8 elems/thread).
__global__ __launch_bounds__(256) void convert_x(const float* __restrict__ X,
                                                 ushort_t* __restrict__ Xb) {
    size_t i = ((size_t)blockIdx.x * 256 + threadIdx.x) * 8;
    float4 a = *(const float4*)(X + i);
    float4 b = *(const float4*)(X + i + 4);
    ushort8 u;
    u[0] = f2bf(a.x); u[1] = f2bf(a.y); u[2] = f2bf(a.z); u[3] = f2bf(a.w);
    u[4] = f2bf(b.x); u[5] = f2bf(b.y); u[6] = f2bf(b.z); u[7] = f2bf(b.w);
    *(ushort8*)(&Xb[i]) = u;
}

// NT GEMM via MFMA bf16: BOTH operands natural bf16, staged with
// global_load_lds using per-lane source addresses (linear LDS dest).
// 2-phase double-buffered (R4-proven: unroll 2 -> static buf indices).
// EPI=0: bf16 natural out. EPI=1: fp32 out + D[col]*Xb epilogue.
template <int EPI>
__global__ __launch_bounds__(256) void gemm_mfma(
    const ushort_t* __restrict__ A, const ushort_t* __restrict__ W,
    void* __restrict__ Cv, const float* __restrict__ Dv,
    const ushort_t* __restrict__ Xb) {
    __shared__ ushort_t Asl[2][4096];   // 8KB/buf: slot = (ks*128+row)*8 ushorts
    __shared__ ushort_t Bsl[2][4096];
    const int tid = threadIdx.x;
    const int rb = blockIdx.x;          // row-panel 0..255
    const int nb = blockIdx.y;          // col-panel 0..3
    const int bm = rb << 7, bn = nb << 7;
    const int lane = tid & 63, wid = tid >> 6;
    const int wr  = (wid >> 1) << 6;
    const int wcc = (wid & 1) << 6;
    const int l16 = lane & 15, ksl = lane >> 4;
    // per-lane natural source offset for chunk c0=tid: row=tid&127, ks=tid>>7
    const int aoff = (tid & 127) * 512 + (tid >> 7) * 8;
    const int ldst = tid * 8;           // LDS ushort offset for c0; c1 at +2048

    f32x4 acc[4][4] = {};

    auto stage = [&](int t, int buf) {
        const ushort_t* pa = A + (size_t)bm * 512 + t * 32 + aoff;
        __builtin_amdgcn_global_load_lds(
            (const __attribute__((address_space(1))) void*)(pa),
            (__attribute__((address_space(3))) void*)(&Asl[buf][ldst]), 16, 0, 0);
        __builtin_amdgcn_global_load_lds(
            (const __attribute__((address_space(1))) void*)(pa + 16),
            (__attribute__((address_space(3))) void*)(&Asl[buf][ldst + 2048]), 16, 0, 0);
        const ushort_t* pb = W + (size_t)bn * 512 + t * 32 + aoff;
        __builtin_amdgcn_global_load_lds(
            (const __attribute__((address_space(1))) void*)(pb),
            (__attribute__((address_space(3))) void*)(&Bsl[buf][ldst]), 16, 0, 0);
        __builtin_amdgcn_global_load_lds(
            (const __attribute__((address_space(1))) void*)(pb + 16),
            (__attribute__((address_space(3))) void*)(&Bsl[buf][ldst + 2048]), 16, 0, 0);
    };

    stage(0, 0);
    __syncthreads();

    int cur = 0;
#pragma unroll 2
    for (int t = 0; t < NTILE; ++t) {
        const int nxt = cur ^ 1;
        if (t + 1 < NTILE) stage(t + 1, nxt);
        short8 afr[4], bfr[4];
#pragma unroll
        for (int m = 0; m < 4; ++m)
            afr[m] = *(const short8*)(&Asl[cur][(ksl * 128 + wr + m * 16 + l16) * 8]);
#pragma unroll
        for (int n = 0; n < 4; ++n)
            bfr[n] = *(const short8*)(&Bsl[cur][(ksl * 128 + wcc + n * 16 + l16) * 8]);
#pragma unroll
        for (int m = 0; m < 4; ++m)
#pragma unroll
            for (int n = 0; n < 4; ++n)
                acc[m][n] = __builtin_amdgcn_mfma_f32_16x16x32_bf16(
                    afr[m], bfr[n], acc[m][n], 0, 0, 0);
        __syncthreads();
        cur = nxt;
    }

    // epilogue: C/D layout col=lane&15, row=(lane>>4)*4+reg
    const int fr = (lane >> 4) << 2;
#pragma unroll
    for (int m = 0; m < 4; ++m) {
#pragma unroll
        for (int n = 0; n < 4; ++n) {
#pragma unroll
            for (int r = 0; r < 4; ++r) {
                int row = bm + wr + m * 16 + fr + r;
                int col = bn + wcc + n * 16 + l16;
                size_t o = (size_t)row * 512 + col;
                float v = acc[m][n][r];
                if constexpr (EPI) {
                    ((float*)Cv)[o] = v + Dv[col] * bf2f(Xb[o]);
                } else {
                    ((ushort_t*)Cv)[o] = f2bf(v);
                }
            }
        }
    }
}

// Pass A: per (chunk c, batch b): 128 threads own h-pairs; packed uint loads.
__global__ __launch_bounds__(128) void scan_local(const float* __restrict__ nu_log,
        const float* __restrict__ theta_log, float* __restrict__ ws) {
    const int c = blockIdx.x >> 4;
    const int b = blockIdx.x & 15;
    const int i = threadIdx.x;          // 0..127
    const int h0 = 2 * i;
    float lr[2], li[2];
#pragma unroll
    for (int q = 0; q < 2; ++q) {
        float nu = expf(nu_log[h0 + q]);
        float th = expf(theta_log[h0 + q]);
        float r  = expf(-nu);
        lr[q] = r * cosf(th); li[q] = r * sinf(th);
    }
    const ushort_t* Bu = (const ushort_t*)(ws + WS_BU);
    float hr[2] = {0.f, 0.f}, hi[2] = {0.f, 0.f};
    const int t0 = c * CHUNK;
    for (int l = 0; l < CHUNK; ++l) {
        size_t base = ((size_t)(t0 + l) * B_DIM + b) * KC;
        unsigned int vre = *(const unsigned int*)(&Bu[base + h0]);
        unsigned int vim = *(const unsigned int*)(&Bu[base + 256 + h0]);
#pragma unroll
        for (int q = 0; q < 2; ++q) {
            float br = bf2f((ushort_t)(q ? (vre >> 16) : (vre & 0xffff)));
            float bi = bf2f((ushort_t)(q ? (vim >> 16) : (vim & 0xffff)));
            float nr = fmaf(lr[q], hr[q], fmaf(-li[q], hi[q], br));
            float ni = fmaf(lr[q], hi[q], fmaf(li[q], hr[q], bi));
            hr[q] = nr; hi[q] = ni;
        }
    }
    size_t cb = ((size_t)(c * B_DIM + b)) * KC;
    *(float2*)(&ws[WS_CARRY + cb + h0])       = make_float2(hr[0], hr[1]);
    *(float2*)(&ws[WS_CARRY + cb + 256 + h0]) = make_float2(hi[0], hi[1]);
}

// Pass B: sequential over 32 chunk aggregates; h_final planar re/im to out tail.
__global__ __launch_bounds__(256) void scan_carry(const float* __restrict__ nu_log,
        const float* __restrict__ theta_log, float* __restrict__ ws,
        const float* __restrict__ h_re, const float* __restrict__ h_im,
        float* __restrict__ out, int out_size) {
    const int b = blockIdx.x;
    const int h = threadIdx.x;
    const float nu = expf(nu_log[h]);
    const float th = expf(theta_log[h]);
    const float rL  = expf(-64.f * nu);
    const float thL = 64.f * th;
    const float Lr = rL * cosf(thL), Li = rL * sinf(thL);
    float cr = h_re[b * H_DIM + h], ci = h_im[b * H_DIM + h];
    for (int c = 0; c < NCHUNK; ++c) {
        size_t cidx = ((size_t)(c * B_DIM + b)) * KC + h;
        float sr = ws[WS_CARRY + cidx], si = ws[WS_CARRY + cidx + 256];
        ws[WS_CARRY + cidx]       = cr;
        ws[WS_CARRY + cidx + 256] = ci;
        float nr = fmaf(Lr, cr, fmaf(-Li, ci, sr));
        float ni = fmaf(Lr, ci, fmaf(Li, cr, si));
        cr = nr; ci = ni;
    }
    const size_t base = (size_t)T_DIM * B_DIM * M_DIM;
    const size_t idx  = (size_t)b * H_DIM + h;
    size_t ore = base + idx;
    size_t oim = base + (size_t)B_DIM * H_DIM + idx;
    if (ore < (size_t)out_size) out[ore] = cr;
    if (oim < (size_t)out_size) out[oim] = ci;
}

// Pass C: replay chunk from carry-in; overwrite Bu IN PLACE with h_t (bf16
// natural layout, packed-uint coalesced stores).
__global__ __launch_bounds__(128) void scan_apply(const float* __restrict__ nu_log,
        const float* __restrict__ theta_log, float* __restrict__ ws) {
    const int c = blockIdx.x >> 4;
    const int b = blockIdx.x & 15;
    const int i = threadIdx.x;          // 0..127
    const int h0 = 2 * i;
    float lr[2], li[2];
#pragma unroll
    for (int q = 0; q < 2; ++q) {
        float nu = expf(nu_log[h0 + q]);
        float th = expf(theta_log[h0 + q]);
        float r  = expf(-nu);
        lr[q] = r * cosf(th); li[q] = r * sinf(th);
    }
    ushort_t* Bu = (ushort_t*)(ws + WS_BU);
    size_t cb = ((size_t)(c * B_DIM + b)) * KC;
    float2 f2r = *(const float2*)(&ws[WS_CARRY + cb + h0]);
    float2 f2i = *(const float2*)(&ws[WS_CARRY + cb + 256 + h0]);
    float hr[2] = {f2r.x, f2r.y}, hi[2] = {f2i.x, f2i.y};
    const int t0 = c * CHUNK;
    for (int l = 0; l < CHUNK; ++l) {
        size_t base = ((size_t)(t0 + l) * B_DIM + b) * KC;
        unsigned int vre = *(const unsigned int*)(&Bu[base + h0]);
        unsigned int vim = *(const unsigned int*)(&Bu[base + 256 + h0]);
#pragma unroll
        for (int q = 0; q < 2; ++q) {
            float br = bf2f((ushort_t)(q ? (vre >> 16) : (vre & 0xffff)));
            float bi = bf2f((ushort_t)(q ? (vim >> 16) : (vim & 0xffff)));
            float nr = fmaf(lr[q], hr[q], fmaf(-li[q], hi[q], br));
            float ni = fmaf(lr[q], hi[q], fmaf(li[q], hr[q], bi));
            hr[q] = nr; hi[q] = ni;
        }
        unsigned int pre = (unsigned int)f2bf(hr[0]) | ((unsigned int)f2bf(hr[1]) << 16);
        unsigned int pim = (unsigned int)f2bf(hi[0]) | ((unsigned int)f2bf(hi[1]) << 16);
        *(unsigned int*)(&Bu[base + h0])       = pre;
        *(unsigned int*)(&Bu[base + 256 + h0]) = pim;
    }
}

extern "C" void kernel_launch(void* const* d_in, const int* in_sizes, int n_in,
                              void* d_out, int out_size, void* d_ws, size_t ws_size,
                              hipStream_t stream) {
    const float* inputs    = (const float*)d_in[0];
    const float* h_re      = (const float*)d_in[1];
    const float* h_im      = (const float*)d_in[2];
    const float* nu_log    = (const float*)d_in[3];
    const float* theta_log = (const float*)d_in[4];
    const float* gamma_log = (const float*)d_in[5];
    const float* B_re      = (const float*)d_in[6];
    const float* B_im      = (const float*)d_in[7];
    const float* C_re      = (const float*)d_in[8];
    const float* C_im      = (const float*)d_in[9];
    const float* Dv        = (const float*)d_in[10];
    float* out = (float*)d_out;
    float* ws  = (float*)d_ws;
    ushort_t* wb = (ushort_t*)(ws + WS_WB_BF);
    ushort_t* wc = (ushort_t*)(ws + WS_WC_BF);
    ushort_t* xb = (ushort_t*)(ws + WS_XB);
    ushort_t* bu = (ushort_t*)(ws + WS_BU);

    prep_w<<<1024, 256, 0, stream>>>(B_re, B_im, gamma_log, C_re, C_im, wb, wc);
    convert_x<<<8192, 256, 0, stream>>>(inputs, xb);

    // GEMM1: Bu[n][j] = X[n][:] . Wb[j][:]  (both operands natural bf16)
    gemm_mfma<0><<<dim3(256, 4), 256, 0, stream>>>(xb, wb, (void*)bu,
                                                   nullptr, nullptr);

    scan_local<<<NCHUNK * B_DIM, 128, 0, stream>>>(nu_log, theta_log, ws);
    scan_carry<<<B_DIM, 256, 0, stream>>>(nu_log, theta_log, ws, h_re, h_im,
                                          out, out_size);
    scan_apply<<<NCHUNK * B_DIM, 128, 0, stream>>>(nu_log, theta_log, ws);

    // GEMM2: Y[n][m] = H[n][:] . Wc[m][:] + D[m]*Xb[n][m]
    gemm_mfma<1><<<dim3(256, 4), 256, 0, stream>>>(bu, wc, (void*)out,
                                                   Dv, xb);
}